// Round 1
// 417.228 us; speedup vs baseline: 1.3155x; 1.3155x over previous
//
#include <hip/hip_runtime.h>
#include <hip/hip_bf16.h>
#include <stdint.h>

#define M_DIM 8192
#define N_DIM 4096
#define K_DIM 4096
#define FP8MAX 448.0f
#define CANARY 0x5CA1AB1Eu

typedef float floatx4 __attribute__((ext_vector_type(4)));
typedef float floatx16 __attribute__((ext_vector_type(16)));
typedef short short8 __attribute__((ext_vector_type(8)));
typedef int int8v __attribute__((ext_vector_type(8)));

// f32 -> bf16 bits, RNE. Exact for fp8-grid values. (fallback path)
__device__ __forceinline__ unsigned int f2bfbits(float f) {
    union { float f; unsigned int u; } v; v.f = f;
    return (v.u + 0x7fffu + ((v.u >> 16) & 1u)) >> 16;
}

// fp32x4 -> e4m3(RNE,sat) -> bf16x4 packed into uint2 (fallback path)
__device__ __forceinline__ uint2 quant4(float a, float b, float c, float d) {
    int p8 = __builtin_amdgcn_cvt_pk_fp8_f32(a, b, 0, false);
    p8 = __builtin_amdgcn_cvt_pk_fp8_f32(c, d, p8, true);
    float qa = __builtin_amdgcn_cvt_f32_fp8(p8, 0);
    float qb = __builtin_amdgcn_cvt_f32_fp8(p8, 1);
    float qc = __builtin_amdgcn_cvt_f32_fp8(p8, 2);
    float qd = __builtin_amdgcn_cvt_f32_fp8(p8, 3);
    return make_uint2(f2bfbits(qa) | (f2bfbits(qb) << 16),
                      f2bfbits(qc) | (f2bfbits(qd) << 16));
}

// fp32x4 -> 4 packed e4m3 bytes (RNE, saturating). Byte i = fp8(arg i).
__device__ __forceinline__ unsigned int quant4_fp8(float a, float b, float c, float d) {
    int p8 = __builtin_amdgcn_cvt_pk_fp8_f32(a, b, 0, false);
    p8 = __builtin_amdgcn_cvt_pk_fp8_f32(c, d, p8, true);
    return (unsigned int)p8;
}

// ================= FP8 compact path: coalesced prepass into ws =================

// x fp32 -> e4m3 bytes in ws; block absmax (of original fp32) -> partials[b]
__global__ __launch_bounds__(256) void quant_x_ws8(const uint4* __restrict__ x,
                                                   unsigned int* __restrict__ xq,
                                                   float* __restrict__ partials) {
    const int tid = blockIdx.x * 256 + threadIdx.x;
    float vmax = 0.f;
    for (int c = tid; c < (M_DIM * K_DIM) / 4; c += 2048 * 256) {
        uint4 v = x[c];
        float a = __uint_as_float(v.x), b = __uint_as_float(v.y);
        float cc = __uint_as_float(v.z), d = __uint_as_float(v.w);
        vmax = fmaxf(vmax, fmaxf(fmaxf(fabsf(a), fabsf(b)), fmaxf(fabsf(cc), fabsf(d))));
        xq[c] = quant4_fp8(a, b, cc, d);
    }
    #pragma unroll
    for (int off = 32; off >= 1; off >>= 1)
        vmax = fmaxf(vmax, __shfl_xor(vmax, off, 64));
    __shared__ float smax[4];
    if ((threadIdx.x & 63) == 0) smax[threadIdx.x >> 6] = vmax;
    __syncthreads();
    if (threadIdx.x == 0)
        partials[blockIdx.x] = fmaxf(fmaxf(smax[0], smax[1]), fmaxf(smax[2], smax[3]));
}

// w fp32 (exact fp8 values) -> e4m3 bytes in ws (cvt is exact on the fp8 grid)
__global__ __launch_bounds__(256) void quant_w_ws8(const uint4* __restrict__ w,
                                                   unsigned int* __restrict__ wq) {
    const int tid = blockIdx.x * 256 + threadIdx.x;
    for (int c = tid; c < (N_DIM * K_DIM) / 4; c += 1024 * 256) {
        uint4 v = w[c];
        wq[c] = quant4_fp8(__uint_as_float(v.x), __uint_as_float(v.y),
                           __uint_as_float(v.z), __uint_as_float(v.w));
    }
}

// reduce 2048 contiguous partials -> scale (+canary) at scb
__global__ __launch_bounds__(256) void scale_ws(const float* __restrict__ partials,
                                                const float* __restrict__ wscale,
                                                float* __restrict__ scb) {
    float vmax = 0.f;
    for (int i = threadIdx.x; i < 2048; i += 256) vmax = fmaxf(vmax, partials[i]);
    #pragma unroll
    for (int off = 32; off >= 1; off >>= 1)
        vmax = fmaxf(vmax, __shfl_xor(vmax, off, 64));
    __shared__ float smax[4];
    if ((threadIdx.x & 63) == 0) smax[threadIdx.x >> 6] = vmax;
    __syncthreads();
    if (threadIdx.x == 0) {
        float m = fmaxf(fmaxf(smax[0], smax[1]), fmaxf(smax[2], smax[3]));
        scb[0] = (fmaxf(m, 1e-12f) / FP8MAX) * wscale[0];
        ((unsigned int*)scb)[1] = CANARY;
    }
}

__device__ __forceinline__ int8v pack8(uint4 u0, uint4 u1) {
    int8v r;
    r[0] = (int)u0.x; r[1] = (int)u0.y; r[2] = (int)u0.z; r[3] = (int)u0.w;
    r[4] = (int)u1.x; r[5] = (int)u1.y; r[6] = (int)u1.z; r[7] = (int)u1.w;
    return r;
}

// ========== FP8 GEMM: 128x128 tile, BK=128 fp8 elems, 2-barrier loop (proven
// structure), mfma_scale_f32_32x32x64_f8f6f4 with unit E8M0 scales (0x7F = 2^0).
// Exact fp8 x fp8 -> fp32 at 2x bf16 rate. LDS rows 128B, XOR-swizzle
// byte ^= (row&7)<<4 on BOTH write and read (4-way residual = floor for b128).
// Any consistent within-K byte permutation of A/B frags cancels (same lane->k
// map used for A and B); only row=lane&31 and the C/D map must be exact.
__global__ __launch_bounds__(256, 2) void gemm_fp8_kernel(
    const unsigned char* __restrict__ Aq,   // [8192][4096] e4m3 bytes
    const unsigned char* __restrict__ Bq,   // [4096][4096] e4m3 bytes
    const unsigned char* __restrict__ scb,
    const float* __restrict__ bias,
    float* __restrict__ out) {
    __shared__ __align__(16) unsigned char lds[2 * 128 * 128];  // A @0, B @16384
    const int tid = threadIdx.x;
    const int l = tid & 63, wv = tid >> 6, wm = wv >> 1, wn = wv & 1;
    const int bm = blockIdx.y, bn = blockIdx.x;
    const int r = tid >> 1, kq = (tid & 1) * 64;   // staging: row r, 64B half

    const float scl = *(const float*)scb;
    const unsigned int canary = *(const unsigned int*)(scb + 4);

    const unsigned char* gA = Aq + (size_t)(bm * 128 + r) * 4096 + kq;
    const unsigned char* gB = Bq + (size_t)(bn * 128 + r) * 4096 + kq;
    const int swzW = (r & 7) << 4;
    unsigned char* sA = lds + r * 128;
    unsigned char* sB = lds + 16384 + r * 128;

    const int swzR = (l & 7) << 4;            // (row&7)<<4: row = ..+ (l&31), 64|32 are mult of 8
    int aBase[2], bBase[2], rdOff[2][2][2];   // [i][s][half]
    #pragma unroll
    for (int i = 0; i < 2; ++i) {
        aBase[i] = (wm * 64 + i * 32 + (l & 31)) * 128;
        bBase[i] = 16384 + (wn * 64 + i * 32 + (l & 31)) * 128;
        #pragma unroll
        for (int s = 0; s < 2; ++s) {
            int off = s * 64 + (l >> 5) * 32;
            rdOff[i][s][0] = (off) ^ swzR;        // explicit XOR on each 16B half:
            rdOff[i][s][1] = (off + 16) ^ swzR;   // keeps k-order row-independent
        }
    }

    floatx16 acc[2][2];
    #pragma unroll
    for (int i = 0; i < 2; ++i)
        #pragma unroll
        for (int j = 0; j < 2; ++j)
            acc[i][j] = (floatx16)0.f;

    for (int kt = 0; kt < K_DIM / 128; ++kt) {
        uint4 a0 = *(const uint4*)(gA);
        uint4 a1 = *(const uint4*)(gA + 16);
        uint4 a2 = *(const uint4*)(gA + 32);
        uint4 a3 = *(const uint4*)(gA + 48);
        uint4 b0 = *(const uint4*)(gB);
        uint4 b1 = *(const uint4*)(gB + 16);
        uint4 b2 = *(const uint4*)(gB + 32);
        uint4 b3 = *(const uint4*)(gB + 48);
        gA += 128;
        gB += 128;
        __syncthreads();           // prior iteration's frag reads done
        *(uint4*)(sA + (((kq +  0) ^ swzW))) = a0;
        *(uint4*)(sA + (((kq + 16) ^ swzW))) = a1;
        *(uint4*)(sA + (((kq + 32) ^ swzW))) = a2;
        *(uint4*)(sA + (((kq + 48) ^ swzW))) = a3;
        *(uint4*)(sB + (((kq +  0) ^ swzW))) = b0;
        *(uint4*)(sB + (((kq + 16) ^ swzW))) = b1;
        *(uint4*)(sB + (((kq + 32) ^ swzW))) = b2;
        *(uint4*)(sB + (((kq + 48) ^ swzW))) = b3;
        __syncthreads();           // tiles visible

        int8v af[2][2], bf[2][2];  // [i|j][s]
        #pragma unroll
        for (int i = 0; i < 2; ++i) {
            #pragma unroll
            for (int s = 0; s < 2; ++s) {
                uint4 u0 = *(const uint4*)(lds + aBase[i] + rdOff[i][s][0]);
                uint4 u1 = *(const uint4*)(lds + aBase[i] + rdOff[i][s][1]);
                af[i][s] = pack8(u0, u1);
                uint4 v0 = *(const uint4*)(lds + bBase[i] + rdOff[i][s][0]);
                uint4 v1 = *(const uint4*)(lds + bBase[i] + rdOff[i][s][1]);
                bf[i][s] = pack8(v0, v1);
            }
        }
        #pragma unroll
        for (int s = 0; s < 2; ++s)
            #pragma unroll
            for (int i = 0; i < 2; ++i)
                #pragma unroll
                for (int j = 0; j < 2; ++j)
                    acc[i][j] = __builtin_amdgcn_mfma_scale_f32_32x32x64_f8f6f4(
                        af[i][s], bf[j][s], acc[i][j],
                        0 /*cbsz: fp8*/, 0 /*blgp: fp8*/,
                        0, 0x7F,   // scale A: E8M0 127 = 1.0
                        0, 0x7F);  // scale B: E8M0 127 = 1.0
    }

    // epilogue + discriminator. Expected scl ~ 3.1e-6.
    float marker = 0.f;
    if (canary != CANARY) marker = 222.f;
    else if (scl != scl || fabsf(scl) > 1e-1f) marker = 1000.f;
    else if (fabsf(scl) > 1e-4f) marker = 777.f;
    else if (fabsf(scl) < 1e-8f) marker = 333.f;

    float bj[2];
    #pragma unroll
    for (int j = 0; j < 2; ++j)
        bj[j] = bias[bn * 128 + wn * 64 + j * 32 + (l & 31)];

    // C/D map (32x32, shape-determined): col=lane&31, row=(reg&3)+8*(reg>>2)+4*(lane>>5)
    #pragma unroll
    for (int i = 0; i < 2; ++i) {
        #pragma unroll
        for (int rg = 0; rg < 4; ++rg) {
            #pragma unroll
            for (int rr = 0; rr < 4; ++rr) {
                int row = bm * 128 + wm * 64 + i * 32 + rg * 8 + rr + 4 * (l >> 5);
                float* orow = out + (size_t)row * N_DIM;
                #pragma unroll
                for (int j = 0; j < 2; ++j) {
                    int col = bn * 128 + wn * 64 + j * 32 + (l & 31);
                    float v = acc[i][j][rg * 4 + rr] * scl + bj[j];
                    if (marker != 0.f) v = marker;
                    else if (bj[j] != bj[j]) v = 111.f;
                    else if (v != v) v = 555.f;
                    orow[col] = v;
                }
            }
        }
    }
}

// ================= Fallback (in-place spread) path: round-6 verbatim =================

__global__ __launch_bounds__(256) void quant_w_kernel(unsigned char* wbuf) {
    const size_t t = (size_t)blockIdx.x * 256 + threadIdx.x;   // 262144 regions
    uint4* p = (uint4*)(wbuf + t * 256);
    uint4 r[16];
    #pragma unroll
    for (int i = 0; i < 16; ++i) r[i] = p[i];
    const float* f = (const float*)r;
    unsigned int o[32];
    #pragma unroll
    for (int i = 0; i < 16; ++i) {
        unsigned int b0 = f2bfbits(f[4 * i + 0]);
        unsigned int b1 = f2bfbits(f[4 * i + 1]);
        unsigned int b2 = f2bfbits(f[4 * i + 2]);
        unsigned int b3 = f2bfbits(f[4 * i + 3]);
        ((uint2*)o)[i] = make_uint2(b0 | (b1 << 16), b2 | (b3 << 16));
    }
    uint4* q = (uint4*)(wbuf + t * 256);
    #pragma unroll
    for (int i = 0; i < 8; ++i) q[i] = ((uint4*)o)[i];
}

__global__ __launch_bounds__(256) void quant_x_kernel(unsigned char* xbuf, unsigned char* wbuf) {
    const size_t t = (size_t)blockIdx.x * 256 + threadIdx.x;   // 524288 regions
    uint4* p = (uint4*)(xbuf + t * 256);
    uint4 r[16];
    #pragma unroll
    for (int i = 0; i < 16; ++i) r[i] = p[i];
    const float* f = (const float*)r;
    float vmax = 0.f;
    unsigned int o[32];
    #pragma unroll
    for (int i = 0; i < 16; ++i) {
        float a = f[4 * i + 0], b = f[4 * i + 1], c = f[4 * i + 2], d = f[4 * i + 3];
        vmax = fmaxf(vmax, fmaxf(fmaxf(fabsf(a), fabsf(b)), fmaxf(fabsf(c), fabsf(d))));
        ((uint2*)o)[i] = quant4(a, b, c, d);
    }
    uint4* q = (uint4*)(xbuf + t * 256);
    #pragma unroll
    for (int i = 0; i < 8; ++i) q[i] = ((uint4*)o)[i];
    #pragma unroll
    for (int off = 32; off >= 1; off >>= 1)
        vmax = fmaxf(vmax, __shfl_xor(vmax, off, 64));
    __shared__ float smax[4];
    if ((threadIdx.x & 63) == 0) smax[threadIdx.x >> 6] = vmax;
    __syncthreads();
    if (threadIdx.x == 0)
        *(float*)(wbuf + ((size_t)blockIdx.x + 1) * 256 + 128) =
            fmaxf(fmaxf(smax[0], smax[1]), fmaxf(smax[2], smax[3]));
}

__global__ __launch_bounds__(256) void scale_kernel(unsigned char* wbuf, const float* wscale) {
    float vmax = 0.f;
    for (int i = threadIdx.x; i < 2048; i += 256)
        vmax = fmaxf(vmax, *(const float*)(wbuf + ((size_t)i + 1) * 256 + 128));
    #pragma unroll
    for (int off = 32; off >= 1; off >>= 1)
        vmax = fmaxf(vmax, __shfl_xor(vmax, off, 64));
    __shared__ float smax[4];
    if ((threadIdx.x & 63) == 0) smax[threadIdx.x >> 6] = vmax;
    __syncthreads();
    if (threadIdx.x == 0) {
        float m = fmaxf(fmaxf(smax[0], smax[1]), fmaxf(smax[2], smax[3]));
        *(float*)(wbuf + 128) = (fmaxf(m, 1e-12f) / FP8MAX) * wscale[0];
        *(unsigned int*)(wbuf + 132) = CANARY;
    }
}

// ========== Fallback GEMM: round-6 structure, strides parametrized ==========
__global__ __launch_bounds__(256, 2) void gemm_bf16_kernel(
    const unsigned char* __restrict__ Aq,
    const unsigned char* __restrict__ Bq,
    int rs, int ktb,
    const unsigned char* __restrict__ scb,
    const float* __restrict__ bias,
    float* __restrict__ out) {
    __shared__ __align__(16) short lds[2 * 128 * 72];   // A @0, B @9216 (shorts)
    const int tid = threadIdx.x;
    const int l = tid & 63, wv = tid >> 6, wm = wv >> 1, wn = wv & 1;
    const int bm = blockIdx.y, bn = blockIdx.x;
    const int r = tid >> 1, kq = (tid & 1) * 64;

    const float scl = *(const float*)scb;
    const unsigned int canary = *(const unsigned int*)(scb + 4);

    const unsigned char* gA = Aq + (size_t)(bm * 128 + r) * rs + kq;
    const unsigned char* gB = Bq + (size_t)(bn * 128 + r) * rs + kq;
    short* sA = lds + r * 72 + kq / 2;
    short* sB = lds + 9216 + r * 72 + kq / 2;

    int aOff[4][2], bOff[4][2];
    #pragma unroll
    for (int i = 0; i < 4; ++i) {
        #pragma unroll
        for (int s = 0; s < 2; ++s) {
            int rowa = wm * 64 + i * 16 + (l & 15);
            aOff[i][s] = rowa * 72 + s * 32 + (l >> 4) * 8;
            int rowb = wn * 64 + i * 16 + (l & 15);
            bOff[i][s] = 9216 + rowb * 72 + s * 32 + (l >> 4) * 8;
        }
    }

    floatx4 acc[4][4];
    #pragma unroll
    for (int i = 0; i < 4; ++i)
        #pragma unroll
        for (int j = 0; j < 4; ++j)
            acc[i][j] = (floatx4)0.f;

    for (int kt = 0; kt < K_DIM / 64; ++kt) {
        uint4 a0 = *(const uint4*)(gA);
        uint4 a1 = *(const uint4*)(gA + 16);
        uint4 a2 = *(const uint4*)(gA + 32);
        uint4 a3 = *(const uint4*)(gA + 48);
        uint4 b0 = *(const uint4*)(gB);
        uint4 b1 = *(const uint4*)(gB + 16);
        uint4 b2 = *(const uint4*)(gB + 32);
        uint4 b3 = *(const uint4*)(gB + 48);
        gA += ktb;
        gB += ktb;
        __syncthreads();
        *(uint4*)(sA +  0) = a0;  *(uint4*)(sA +  8) = a1;
        *(uint4*)(sA + 16) = a2;  *(uint4*)(sA + 24) = a3;
        *(uint4*)(sB +  0) = b0;  *(uint4*)(sB +  8) = b1;
        *(uint4*)(sB + 16) = b2;  *(uint4*)(sB + 24) = b3;
        __syncthreads();

        short8 af[4][2], bf[4][2];
        #pragma unroll
        for (int i = 0; i < 4; ++i) {
            af[i][0] = *(const short8*)(lds + aOff[i][0]);
            af[i][1] = *(const short8*)(lds + aOff[i][1]);
            bf[i][0] = *(const short8*)(lds + bOff[i][0]);
            bf[i][1] = *(const short8*)(lds + bOff[i][1]);
        }
        #pragma unroll
        for (int s = 0; s < 2; ++s)
            #pragma unroll
            for (int i = 0; i < 4; ++i)
                #pragma unroll
                for (int j = 0; j < 4; ++j)
                    acc[i][j] = __builtin_amdgcn_mfma_f32_16x16x32_bf16(
                        af[i][s], bf[j][s], acc[i][j], 0, 0, 0);
    }

    float marker = 0.f;
    if (canary != CANARY) marker = 222.f;
    else if (scl != scl || fabsf(scl) > 1e-1f) marker = 1000.f;
    else if (fabsf(scl) > 1e-4f) marker = 777.f;
    else if (fabsf(scl) < 1e-8f) marker = 333.f;

    float bj[4];
    #pragma unroll
    for (int j = 0; j < 4; ++j) {
        int col = bn * 128 + wn * 64 + j * 16 + (l & 15);
        bj[j] = bias[col];
    }
    #pragma unroll
    for (int i = 0; i < 4; ++i) {
        #pragma unroll
        for (int rr = 0; rr < 4; ++rr) {
            int row = bm * 128 + wm * 64 + i * 16 + (l >> 4) * 4 + rr;
            float* orow = out + (size_t)row * N_DIM;
            #pragma unroll
            for (int j = 0; j < 4; ++j) {
                int col = bn * 128 + wn * 64 + j * 16 + (l & 15);
                float v = acc[i][j][rr] * scl + bj[j];
                if (marker != 0.f) v = marker;
                else if (bj[j] != bj[j]) v = 111.f;
                else if (v != v) v = 555.f;
                orow[col] = v;
            }
        }
    }
}

extern "C" void kernel_launch(void* const* d_in, const int* in_sizes, int n_in,
                              void* d_out, int out_size, void* d_ws, size_t ws_size,
                              hipStream_t stream) {
    unsigned char* x = (unsigned char*)d_in[0];   // fp32 [8192][4096] (fp16 promoted)
    unsigned char* w = (unsigned char*)d_in[1];   // fp32 exact-fp8 [4096][4096]
    const float* wscale = (const float*)d_in[2];  // fp32 [1]
    const float* bias = (const float*)d_in[3];    // fp32 [4096] (fp16 promoted)
    float* out = (float*)d_out;                   // fp32 [8192][4096]

    const size_t XQ8 = (size_t)M_DIM * K_DIM;     // 32MB fp8 x
    const size_t WQ8 = (size_t)N_DIM * K_DIM;     // 16MB fp8 w
    unsigned char* ws = (unsigned char*)d_ws;

    if (ws_size >= XQ8 + WQ8 + 2048 * 4 + 64) {
        // ---- fp8 compact path: coalesced prepass into ws, MX-fp8 GEMM ----
        unsigned char* xq = ws;
        unsigned char* wq = ws + XQ8;
        float* partials = (float*)(ws + XQ8 + WQ8);
        unsigned char* scb = ws + XQ8 + WQ8 + 8192;
        quant_w_ws8<<<1024, 256, 0, stream>>>((const uint4*)w, (unsigned int*)wq);
        quant_x_ws8<<<2048, 256, 0, stream>>>((const uint4*)x, (unsigned int*)xq, partials);
        scale_ws<<<1, 256, 0, stream>>>(partials, wscale, (float*)scb);
        gemm_fp8_kernel<<<dim3(N_DIM / 128, M_DIM / 128), 256, 0, stream>>>(
            xq, wq, scb, bias, out);
    } else {
        // ---- fallback: round-6 in-place spread path (proven) ----
        quant_w_kernel<<<1024, 256, 0, stream>>>(w);
        quant_x_kernel<<<2048, 256, 0, stream>>>(x, w);
        scale_kernel<<<1, 256, 0, stream>>>(w, wscale);
        gemm_bf16_kernel<<<dim3(N_DIM / 128, M_DIM / 128), 256, 0, stream>>>(
            x, w, 16384, 256, w + 128, bias, out);
    }
}

// Round 2
// 414.502 us; speedup vs baseline: 1.3242x; 1.0066x over previous
//
#include <hip/hip_runtime.h>
#include <hip/hip_bf16.h>
#include <stdint.h>

#define M_DIM 8192
#define N_DIM 4096
#define K_DIM 4096
#define FP8MAX 448.0f
#define CANARY 0x5CA1AB1Eu

typedef float floatx4 __attribute__((ext_vector_type(4)));
typedef float floatx16 __attribute__((ext_vector_type(16)));
typedef short short8 __attribute__((ext_vector_type(8)));
typedef int int8v __attribute__((ext_vector_type(8)));

// f32 -> bf16 bits, RNE. Exact for fp8-grid values. (fallback path)
__device__ __forceinline__ unsigned int f2bfbits(float f) {
    union { float f; unsigned int u; } v; v.f = f;
    return (v.u + 0x7fffu + ((v.u >> 16) & 1u)) >> 16;
}

// fp32x4 -> e4m3(RNE,sat) -> bf16x4 packed into uint2 (fallback path)
__device__ __forceinline__ uint2 quant4(float a, float b, float c, float d) {
    int p8 = __builtin_amdgcn_cvt_pk_fp8_f32(a, b, 0, false);
    p8 = __builtin_amdgcn_cvt_pk_fp8_f32(c, d, p8, true);
    float qa = __builtin_amdgcn_cvt_f32_fp8(p8, 0);
    float qb = __builtin_amdgcn_cvt_f32_fp8(p8, 1);
    float qc = __builtin_amdgcn_cvt_f32_fp8(p8, 2);
    float qd = __builtin_amdgcn_cvt_f32_fp8(p8, 3);
    return make_uint2(f2bfbits(qa) | (f2bfbits(qb) << 16),
                      f2bfbits(qc) | (f2bfbits(qd) << 16));
}

// uint4 of 4 fp32 -> 4 packed e4m3 bytes (RNE, saturating)
__device__ __forceinline__ unsigned int q4(uint4 v) {
    int p8 = __builtin_amdgcn_cvt_pk_fp8_f32(__uint_as_float(v.x), __uint_as_float(v.y), 0, false);
    p8 = __builtin_amdgcn_cvt_pk_fp8_f32(__uint_as_float(v.z), __uint_as_float(v.w), p8, true);
    return (unsigned int)p8;
}

__device__ __forceinline__ float amax4(uint4 v, float m) {
    float a = fabsf(__uint_as_float(v.x)), b = fabsf(__uint_as_float(v.y));
    float c = fabsf(__uint_as_float(v.z)), d = fabsf(__uint_as_float(v.w));
    return fmaxf(m, fmaxf(fmaxf(a, b), fmaxf(c, d)));
}

// ============ Fused prepass: w-quant (blocks 0..1023) + x-quant+absmax ============
// Widened: each thread per iter reads 4x uint4 (64B fp32) and writes 1x uint4 (16 fp8).
__global__ __launch_bounds__(256) void quant_fused(const uint4* __restrict__ x,
                                                   const uint4* __restrict__ w,
                                                   uint4* __restrict__ xq,
                                                   uint4* __restrict__ wq,
                                                   float* __restrict__ partials) {
    if (blockIdx.x < 1024) {
        // ---- w: fp32 exact-fp8 values -> e4m3 bytes (cvt exact on fp8 grid) ----
        const int tid = blockIdx.x * 256 + threadIdx.x;        // 262144 threads
        for (int c = tid; c < (N_DIM * K_DIM) / 16; c += 1024 * 256) {
            uint4 v0 = w[4 * c + 0], v1 = w[4 * c + 1];
            uint4 v2 = w[4 * c + 2], v3 = w[4 * c + 3];
            wq[c] = make_uint4(q4(v0), q4(v1), q4(v2), q4(v3));
        }
    } else {
        // ---- x: fp32 -> e4m3 bytes; absmax of original fp32 -> partials ----
        const int b = blockIdx.x - 1024;                        // 0..2047
        const int tid = b * 256 + threadIdx.x;                  // 524288 threads
        float vmax = 0.f;
        for (int c = tid; c < (M_DIM * K_DIM) / 16; c += 2048 * 256) {
            uint4 v0 = x[4 * c + 0], v1 = x[4 * c + 1];
            uint4 v2 = x[4 * c + 2], v3 = x[4 * c + 3];
            vmax = amax4(v0, vmax); vmax = amax4(v1, vmax);
            vmax = amax4(v2, vmax); vmax = amax4(v3, vmax);
            xq[c] = make_uint4(q4(v0), q4(v1), q4(v2), q4(v3));
        }
        #pragma unroll
        for (int off = 32; off >= 1; off >>= 1)
            vmax = fmaxf(vmax, __shfl_xor(vmax, off, 64));
        __shared__ float smax[4];
        if ((threadIdx.x & 63) == 0) smax[threadIdx.x >> 6] = vmax;
        __syncthreads();
        if (threadIdx.x == 0)
            partials[b] = fmaxf(fmaxf(smax[0], smax[1]), fmaxf(smax[2], smax[3]));
    }
}

__device__ __forceinline__ int8v pack8(uint4 u0, uint4 u1) {
    int8v r;
    r[0] = (int)u0.x; r[1] = (int)u0.y; r[2] = (int)u0.z; r[3] = (int)u0.w;
    r[4] = (int)u1.x; r[5] = (int)u1.y; r[6] = (int)u1.z; r[7] = (int)u1.w;
    return r;
}

// ========== FP8 GEMM: proven 2-barrier 128x128 structure (round-1 verbatim main
// loop), mfma_scale_f32_32x32x64_f8f6f4 with unit E8M0 scales. Scale is now
// computed in the epilogue from the 2048 partials (removes the 1-block
// scale_ws dispatch that drained the device between two full-device kernels).
__global__ __launch_bounds__(256, 2) void gemm_fp8_kernel(
    const unsigned char* __restrict__ Aq,   // [8192][4096] e4m3 bytes
    const unsigned char* __restrict__ Bq,   // [4096][4096] e4m3 bytes
    const float* __restrict__ partials,     // 2048 block absmaxes of x
    const float* __restrict__ wscale,
    const float* __restrict__ bias,
    float* __restrict__ out) {
    __shared__ __align__(16) unsigned char lds[2 * 128 * 128];  // A @0, B @16384
    const int tid = threadIdx.x;
    const int l = tid & 63, wv = tid >> 6, wm = wv >> 1, wn = wv & 1;
    const int bm = blockIdx.y, bn = blockIdx.x;
    const int r = tid >> 1, kq = (tid & 1) * 64;   // staging: row r, 64B half

    const unsigned char* gA = Aq + (size_t)(bm * 128 + r) * 4096 + kq;
    const unsigned char* gB = Bq + (size_t)(bn * 128 + r) * 4096 + kq;
    const int swzW = (r & 7) << 4;
    unsigned char* sA = lds + r * 128;
    unsigned char* sB = lds + 16384 + r * 128;

    const int swzR = (l & 7) << 4;            // (row&7)<<4: row = ..+ (l&31)
    int aBase[2], bBase[2], rdOff[2][2][2];   // [i][s][half]
    #pragma unroll
    for (int i = 0; i < 2; ++i) {
        aBase[i] = (wm * 64 + i * 32 + (l & 31)) * 128;
        bBase[i] = 16384 + (wn * 64 + i * 32 + (l & 31)) * 128;
        #pragma unroll
        for (int s = 0; s < 2; ++s) {
            int off = s * 64 + (l >> 5) * 32;
            rdOff[i][s][0] = (off) ^ swzR;
            rdOff[i][s][1] = (off + 16) ^ swzR;
        }
    }

    floatx16 acc[2][2];
    #pragma unroll
    for (int i = 0; i < 2; ++i)
        #pragma unroll
        for (int j = 0; j < 2; ++j)
            acc[i][j] = (floatx16)0.f;

    for (int kt = 0; kt < K_DIM / 128; ++kt) {
        uint4 a0 = *(const uint4*)(gA);
        uint4 a1 = *(const uint4*)(gA + 16);
        uint4 a2 = *(const uint4*)(gA + 32);
        uint4 a3 = *(const uint4*)(gA + 48);
        uint4 b0 = *(const uint4*)(gB);
        uint4 b1 = *(const uint4*)(gB + 16);
        uint4 b2 = *(const uint4*)(gB + 32);
        uint4 b3 = *(const uint4*)(gB + 48);
        gA += 128;
        gB += 128;
        __syncthreads();           // prior iteration's frag reads done
        *(uint4*)(sA + (((kq +  0) ^ swzW))) = a0;
        *(uint4*)(sA + (((kq + 16) ^ swzW))) = a1;
        *(uint4*)(sA + (((kq + 32) ^ swzW))) = a2;
        *(uint4*)(sA + (((kq + 48) ^ swzW))) = a3;
        *(uint4*)(sB + (((kq +  0) ^ swzW))) = b0;
        *(uint4*)(sB + (((kq + 16) ^ swzW))) = b1;
        *(uint4*)(sB + (((kq + 32) ^ swzW))) = b2;
        *(uint4*)(sB + (((kq + 48) ^ swzW))) = b3;
        __syncthreads();           // tiles visible

        int8v af[2][2], bf[2][2];  // [i|j][s]
        #pragma unroll
        for (int i = 0; i < 2; ++i) {
            #pragma unroll
            for (int s = 0; s < 2; ++s) {
                uint4 u0 = *(const uint4*)(lds + aBase[i] + rdOff[i][s][0]);
                uint4 u1 = *(const uint4*)(lds + aBase[i] + rdOff[i][s][1]);
                af[i][s] = pack8(u0, u1);
                uint4 v0 = *(const uint4*)(lds + bBase[i] + rdOff[i][s][0]);
                uint4 v1 = *(const uint4*)(lds + bBase[i] + rdOff[i][s][1]);
                bf[i][s] = pack8(v0, v1);
            }
        }
        #pragma unroll
        for (int s = 0; s < 2; ++s)
            #pragma unroll
            for (int i = 0; i < 2; ++i)
                #pragma unroll
                for (int j = 0; j < 2; ++j)
                    acc[i][j] = __builtin_amdgcn_mfma_scale_f32_32x32x64_f8f6f4(
                        af[i][s], bf[j][s], acc[i][j],
                        0 /*cbsz: fp8*/, 0 /*blgp: fp8*/,
                        0, 0x7F,   // scale A: E8M0 127 = 1.0
                        0, 0x7F);  // scale B: E8M0 127 = 1.0
    }

    // ---- epilogue scale: reduce 2048 partials (L2-hot, coalesced) ----
    float pm = 0.f;
    #pragma unroll
    for (int i = 0; i < 8; ++i) pm = fmaxf(pm, partials[tid + 256 * i]);
    #pragma unroll
    for (int off = 32; off >= 1; off >>= 1)
        pm = fmaxf(pm, __shfl_xor(pm, off, 64));
    __shared__ float sred[5];
    if ((tid & 63) == 0) sred[tid >> 6] = pm;
    __syncthreads();
    if (tid == 0) {
        float m = fmaxf(fmaxf(sred[0], sred[1]), fmaxf(sred[2], sred[3]));
        sred[4] = (fmaxf(m, 1e-12f) / FP8MAX) * wscale[0];
    }
    __syncthreads();
    const float scl = sred[4];

    // discriminator. Expected scl ~ 3.1e-6.
    float marker = 0.f;
    if (scl != scl || fabsf(scl) > 1e-1f) marker = 1000.f;
    else if (fabsf(scl) > 1e-4f) marker = 777.f;
    else if (fabsf(scl) < 1e-8f) marker = 333.f;

    float bj[2];
    #pragma unroll
    for (int j = 0; j < 2; ++j)
        bj[j] = bias[bn * 128 + wn * 64 + j * 32 + (l & 31)];

    // C/D map (32x32, shape-determined): col=lane&31, row=(reg&3)+8*(reg>>2)+4*(lane>>5)
    #pragma unroll
    for (int i = 0; i < 2; ++i) {
        #pragma unroll
        for (int rg = 0; rg < 4; ++rg) {
            #pragma unroll
            for (int rr = 0; rr < 4; ++rr) {
                int row = bm * 128 + wm * 64 + i * 32 + rg * 8 + rr + 4 * (l >> 5);
                float* orow = out + (size_t)row * N_DIM;
                #pragma unroll
                for (int j = 0; j < 2; ++j) {
                    int col = bn * 128 + wn * 64 + j * 32 + (l & 31);
                    float v = acc[i][j][rg * 4 + rr] * scl + bj[j];
                    if (marker != 0.f) v = marker;
                    else if (bj[j] != bj[j]) v = 111.f;
                    else if (v != v) v = 555.f;
                    orow[col] = v;
                }
            }
        }
    }
}

// ================= Fallback (in-place spread) path: round-6 verbatim =================

__global__ __launch_bounds__(256) void quant_w_kernel(unsigned char* wbuf) {
    const size_t t = (size_t)blockIdx.x * 256 + threadIdx.x;   // 262144 regions
    uint4* p = (uint4*)(wbuf + t * 256);
    uint4 r[16];
    #pragma unroll
    for (int i = 0; i < 16; ++i) r[i] = p[i];
    const float* f = (const float*)r;
    unsigned int o[32];
    #pragma unroll
    for (int i = 0; i < 16; ++i) {
        unsigned int b0 = f2bfbits(f[4 * i + 0]);
        unsigned int b1 = f2bfbits(f[4 * i + 1]);
        unsigned int b2 = f2bfbits(f[4 * i + 2]);
        unsigned int b3 = f2bfbits(f[4 * i + 3]);
        ((uint2*)o)[i] = make_uint2(b0 | (b1 << 16), b2 | (b3 << 16));
    }
    uint4* q = (uint4*)(wbuf + t * 256);
    #pragma unroll
    for (int i = 0; i < 8; ++i) q[i] = ((uint4*)o)[i];
}

__global__ __launch_bounds__(256) void quant_x_kernel(unsigned char* xbuf, unsigned char* wbuf) {
    const size_t t = (size_t)blockIdx.x * 256 + threadIdx.x;   // 524288 regions
    uint4* p = (uint4*)(xbuf + t * 256);
    uint4 r[16];
    #pragma unroll
    for (int i = 0; i < 16; ++i) r[i] = p[i];
    const float* f = (const float*)r;
    float vmax = 0.f;
    unsigned int o[32];
    #pragma unroll
    for (int i = 0; i < 16; ++i) {
        float a = f[4 * i + 0], b = f[4 * i + 1], c = f[4 * i + 2], d = f[4 * i + 3];
        vmax = fmaxf(vmax, fmaxf(fmaxf(fabsf(a), fabsf(b)), fmaxf(fabsf(c), fabsf(d))));
        ((uint2*)o)[i] = quant4(a, b, c, d);
    }
    uint4* q = (uint4*)(xbuf + t * 256);
    #pragma unroll
    for (int i = 0; i < 8; ++i) q[i] = ((uint4*)o)[i];
    #pragma unroll
    for (int off = 32; off >= 1; off >>= 1)
        vmax = fmaxf(vmax, __shfl_xor(vmax, off, 64));
    __shared__ float smax[4];
    if ((threadIdx.x & 63) == 0) smax[threadIdx.x >> 6] = vmax;
    __syncthreads();
    if (threadIdx.x == 0)
        *(float*)(wbuf + ((size_t)blockIdx.x + 1) * 256 + 128) =
            fmaxf(fmaxf(smax[0], smax[1]), fmaxf(smax[2], smax[3]));
}

__global__ __launch_bounds__(256) void scale_kernel(unsigned char* wbuf, const float* wscale) {
    float vmax = 0.f;
    for (int i = threadIdx.x; i < 2048; i += 256)
        vmax = fmaxf(vmax, *(const float*)(wbuf + ((size_t)i + 1) * 256 + 128));
    #pragma unroll
    for (int off = 32; off >= 1; off >>= 1)
        vmax = fmaxf(vmax, __shfl_xor(vmax, off, 64));
    __shared__ float smax[4];
    if ((threadIdx.x & 63) == 0) smax[threadIdx.x >> 6] = vmax;
    __syncthreads();
    if (threadIdx.x == 0) {
        float m = fmaxf(fmaxf(smax[0], smax[1]), fmaxf(smax[2], smax[3]));
        *(float*)(wbuf + 128) = (fmaxf(m, 1e-12f) / FP8MAX) * wscale[0];
        *(unsigned int*)(wbuf + 132) = CANARY;
    }
}

// ========== Fallback GEMM: round-6 structure, strides parametrized ==========
__global__ __launch_bounds__(256, 2) void gemm_bf16_kernel(
    const unsigned char* __restrict__ Aq,
    const unsigned char* __restrict__ Bq,
    int rs, int ktb,
    const unsigned char* __restrict__ scb,
    const float* __restrict__ bias,
    float* __restrict__ out) {
    __shared__ __align__(16) short lds[2 * 128 * 72];   // A @0, B @9216 (shorts)
    const int tid = threadIdx.x;
    const int l = tid & 63, wv = tid >> 6, wm = wv >> 1, wn = wv & 1;
    const int bm = blockIdx.y, bn = blockIdx.x;
    const int r = tid >> 1, kq = (tid & 1) * 64;

    const float scl = *(const float*)scb;
    const unsigned int canary = *(const unsigned int*)(scb + 4);

    const unsigned char* gA = Aq + (size_t)(bm * 128 + r) * rs + kq;
    const unsigned char* gB = Bq + (size_t)(bn * 128 + r) * rs + kq;
    short* sA = lds + r * 72 + kq / 2;
    short* sB = lds + 9216 + r * 72 + kq / 2;

    int aOff[4][2], bOff[4][2];
    #pragma unroll
    for (int i = 0; i < 4; ++i) {
        #pragma unroll
        for (int s = 0; s < 2; ++s) {
            int rowa = wm * 64 + i * 16 + (l & 15);
            aOff[i][s] = rowa * 72 + s * 32 + (l >> 4) * 8;
            int rowb = wn * 64 + i * 16 + (l & 15);
            bOff[i][s] = 9216 + rowb * 72 + s * 32 + (l >> 4) * 8;
        }
    }

    floatx4 acc[4][4];
    #pragma unroll
    for (int i = 0; i < 4; ++i)
        #pragma unroll
        for (int j = 0; j < 4; ++j)
            acc[i][j] = (floatx4)0.f;

    for (int kt = 0; kt < K_DIM / 64; ++kt) {
        uint4 a0 = *(const uint4*)(gA);
        uint4 a1 = *(const uint4*)(gA + 16);
        uint4 a2 = *(const uint4*)(gA + 32);
        uint4 a3 = *(const uint4*)(gA + 48);
        uint4 b0 = *(const uint4*)(gB);
        uint4 b1 = *(const uint4*)(gB + 16);
        uint4 b2 = *(const uint4*)(gB + 32);
        uint4 b3 = *(const uint4*)(gB + 48);
        gA += ktb;
        gB += ktb;
        __syncthreads();
        *(uint4*)(sA +  0) = a0;  *(uint4*)(sA +  8) = a1;
        *(uint4*)(sA + 16) = a2;  *(uint4*)(sA + 24) = a3;
        *(uint4*)(sB +  0) = b0;  *(uint4*)(sB +  8) = b1;
        *(uint4*)(sB + 16) = b2;  *(uint4*)(sB + 24) = b3;
        __syncthreads();

        short8 af[4][2], bf[4][2];
        #pragma unroll
        for (int i = 0; i < 4; ++i) {
            af[i][0] = *(const short8*)(lds + aOff[i][0]);
            af[i][1] = *(const short8*)(lds + aOff[i][1]);
            bf[i][0] = *(const short8*)(lds + bOff[i][0]);
            bf[i][1] = *(const short8*)(lds + bOff[i][1]);
        }
        #pragma unroll
        for (int s = 0; s < 2; ++s)
            #pragma unroll
            for (int i = 0; i < 4; ++i)
                #pragma unroll
                for (int j = 0; j < 4; ++j)
                    acc[i][j] = __builtin_amdgcn_mfma_f32_16x16x32_bf16(
                        af[i][s], bf[j][s], acc[i][j], 0, 0, 0);
    }

    float marker = 0.f;
    if (canary != CANARY) marker = 222.f;
    else if (scl != scl || fabsf(scl) > 1e-1f) marker = 1000.f;
    else if (fabsf(scl) > 1e-4f) marker = 777.f;
    else if (fabsf(scl) < 1e-8f) marker = 333.f;

    float bj[4];
    #pragma unroll
    for (int j = 0; j < 4; ++j) {
        int col = bn * 128 + wn * 64 + j * 16 + (l & 15);
        bj[j] = bias[col];
    }
    #pragma unroll
    for (int i = 0; i < 4; ++i) {
        #pragma unroll
        for (int rr = 0; rr < 4; ++rr) {
            int row = bm * 128 + wm * 64 + i * 16 + (l >> 4) * 4 + rr;
            float* orow = out + (size_t)row * N_DIM;
            #pragma unroll
            for (int j = 0; j < 4; ++j) {
                int col = bn * 128 + wn * 64 + j * 16 + (l & 15);
                float v = acc[i][j][rr] * scl + bj[j];
                if (marker != 0.f) v = marker;
                else if (bj[j] != bj[j]) v = 111.f;
                else if (v != v) v = 555.f;
                orow[col] = v;
            }
        }
    }
}

extern "C" void kernel_launch(void* const* d_in, const int* in_sizes, int n_in,
                              void* d_out, int out_size, void* d_ws, size_t ws_size,
                              hipStream_t stream) {
    unsigned char* x = (unsigned char*)d_in[0];   // fp32 [8192][4096] (fp16 promoted)
    unsigned char* w = (unsigned char*)d_in[1];   // fp32 exact-fp8 [4096][4096]
    const float* wscale = (const float*)d_in[2];  // fp32 [1]
    const float* bias = (const float*)d_in[3];    // fp32 [4096] (fp16 promoted)
    float* out = (float*)d_out;                   // fp32 [8192][4096]

    const size_t XQ8 = (size_t)M_DIM * K_DIM;     // 32MB fp8 x
    const size_t WQ8 = (size_t)N_DIM * K_DIM;     // 16MB fp8 w
    unsigned char* ws = (unsigned char*)d_ws;

    if (ws_size >= XQ8 + WQ8 + 2048 * 4 + 64) {
        // ---- fp8 compact path: one fused prepass kernel, MX-fp8 GEMM with
        //      epilogue scale reduction (2 dispatches total) ----
        unsigned char* xq = ws;
        unsigned char* wq = ws + XQ8;
        float* partials = (float*)(ws + XQ8 + WQ8);
        quant_fused<<<3072, 256, 0, stream>>>((const uint4*)x, (const uint4*)w,
                                              (uint4*)xq, (uint4*)wq, partials);
        gemm_fp8_kernel<<<dim3(N_DIM / 128, M_DIM / 128), 256, 0, stream>>>(
            xq, wq, partials, wscale, bias, out);
    } else {
        // ---- fallback: round-6 in-place spread path (proven) ----
        quant_w_kernel<<<1024, 256, 0, stream>>>(w);
        quant_x_kernel<<<2048, 256, 0, stream>>>(x, w);
        scale_kernel<<<1, 256, 0, stream>>>(w, wscale);
        gemm_bf16_kernel<<<dim3(N_DIM / 128, M_DIM / 128), 256, 0, stream>>>(
            x, w, 16384, 256, w + 128, bias, out);
    }
}

// Round 3
// 394.001 us; speedup vs baseline: 1.3931x; 1.0520x over previous
//
#include <hip/hip_runtime.h>
#include <hip/hip_bf16.h>
#include <stdint.h>

#define M_DIM 8192
#define N_DIM 4096
#define K_DIM 4096
#define FP8MAX 448.0f
#define CANARY 0x5CA1AB1Eu

typedef float floatx4 __attribute__((ext_vector_type(4)));
typedef float floatx16 __attribute__((ext_vector_type(16)));
typedef short short8 __attribute__((ext_vector_type(8)));
typedef int int8v __attribute__((ext_vector_type(8)));

// f32 -> bf16 bits, RNE. Exact for fp8-grid values. (fallback path)
__device__ __forceinline__ unsigned int f2bfbits(float f) {
    union { float f; unsigned int u; } v; v.f = f;
    return (v.u + 0x7fffu + ((v.u >> 16) & 1u)) >> 16;
}

// fp32x4 -> e4m3(RNE,sat) -> bf16x4 packed into uint2 (fallback path)
__device__ __forceinline__ uint2 quant4(float a, float b, float c, float d) {
    int p8 = __builtin_amdgcn_cvt_pk_fp8_f32(a, b, 0, false);
    p8 = __builtin_amdgcn_cvt_pk_fp8_f32(c, d, p8, true);
    float qa = __builtin_amdgcn_cvt_f32_fp8(p8, 0);
    float qb = __builtin_amdgcn_cvt_f32_fp8(p8, 1);
    float qc = __builtin_amdgcn_cvt_f32_fp8(p8, 2);
    float qd = __builtin_amdgcn_cvt_f32_fp8(p8, 3);
    return make_uint2(f2bfbits(qa) | (f2bfbits(qb) << 16),
                      f2bfbits(qc) | (f2bfbits(qd) << 16));
}

// uint4 of 4 fp32 -> 4 packed e4m3 bytes (RNE, saturating)
__device__ __forceinline__ unsigned int q4(uint4 v) {
    int p8 = __builtin_amdgcn_cvt_pk_fp8_f32(__uint_as_float(v.x), __uint_as_float(v.y), 0, false);
    p8 = __builtin_amdgcn_cvt_pk_fp8_f32(__uint_as_float(v.z), __uint_as_float(v.w), p8, true);
    return (unsigned int)p8;
}

__device__ __forceinline__ float amax4(uint4 v, float m) {
    float a = fabsf(__uint_as_float(v.x)), b = fabsf(__uint_as_float(v.y));
    float c = fabsf(__uint_as_float(v.z)), d = fabsf(__uint_as_float(v.w));
    return fmaxf(m, fmaxf(fmaxf(a, b), fmaxf(c, d)));
}

// ============ Fused prepass: w-quant (blocks 0..1023) + x-quant+absmax ============
// x absmax published via device-scope atomicMax on positive-float bits (monotonic
// for >=0 floats); scb[0] pre-zeroed by a 4-byte hipMemsetAsync in kernel_launch.
__global__ __launch_bounds__(256) void quant_fused(const uint4* __restrict__ x,
                                                   const uint4* __restrict__ w,
                                                   uint4* __restrict__ xq,
                                                   uint4* __restrict__ wq,
                                                   unsigned int* __restrict__ scb) {
    if (blockIdx.x < 1024) {
        // ---- w: fp32 exact-fp8 values -> e4m3 bytes (cvt exact on fp8 grid) ----
        const int tid = blockIdx.x * 256 + threadIdx.x;        // 262144 threads
        for (int c = tid; c < (N_DIM * K_DIM) / 16; c += 1024 * 256) {
            uint4 v0 = w[4 * c + 0], v1 = w[4 * c + 1];
            uint4 v2 = w[4 * c + 2], v3 = w[4 * c + 3];
            wq[c] = make_uint4(q4(v0), q4(v1), q4(v2), q4(v3));
        }
    } else {
        // ---- x: fp32 -> e4m3 bytes; absmax of original fp32 -> scb ----
        const int b = blockIdx.x - 1024;                        // 0..2047
        const int tid = b * 256 + threadIdx.x;                  // 524288 threads
        float vmax = 0.f;
        for (int c = tid; c < (M_DIM * K_DIM) / 16; c += 2048 * 256) {
            uint4 v0 = x[4 * c + 0], v1 = x[4 * c + 1];
            uint4 v2 = x[4 * c + 2], v3 = x[4 * c + 3];
            vmax = amax4(v0, vmax); vmax = amax4(v1, vmax);
            vmax = amax4(v2, vmax); vmax = amax4(v3, vmax);
            xq[c] = make_uint4(q4(v0), q4(v1), q4(v2), q4(v3));
        }
        #pragma unroll
        for (int off = 32; off >= 1; off >>= 1)
            vmax = fmaxf(vmax, __shfl_xor(vmax, off, 64));
        __shared__ float smax[4];
        if ((threadIdx.x & 63) == 0) smax[threadIdx.x >> 6] = vmax;
        __syncthreads();
        if (threadIdx.x == 0) {
            float m = fmaxf(fmaxf(smax[0], smax[1]), fmaxf(smax[2], smax[3]));
            atomicMax(scb, __float_as_uint(m));   // bits monotonic for m >= 0
        }
    }
}

__device__ __forceinline__ int8v pack8(uint4 u0, uint4 u1) {
    int8v r;
    r[0] = (int)u0.x; r[1] = (int)u0.y; r[2] = (int)u0.z; r[3] = (int)u0.w;
    r[4] = (int)u1.x; r[5] = (int)u1.y; r[6] = (int)u1.z; r[7] = (int)u1.w;
    return r;
}

// ========== FP8 GEMM: 2-barrier 128x128 structure; staging now via
// global_load_lds width=16 (linear LDS dest, pre-swizzled global source — the
// m151/m173 pattern). Read side byte-identical to the proven round-1/2 kernel:
// lds[row*128 + (col ^ ((row&7)<<4))]. Staging map (verified algebraically):
// wave w, instr i, lane l -> LDS byte 4096w+1024i+16l = row 32w+8i+(l>>3),
// col 16(l&7); row&7 == l>>3, so source col = 16(l&7) ^ ((l>>3)<<4).
__global__ __launch_bounds__(256, 2) void gemm_fp8_kernel(
    const unsigned char* __restrict__ Aq,   // [8192][4096] e4m3 bytes
    const unsigned char* __restrict__ Bq,   // [4096][4096] e4m3 bytes
    const unsigned int* __restrict__ scb,   // absmax(x) bits
    const float* __restrict__ wscale,
    const float* __restrict__ bias,
    float* __restrict__ out) {
    __shared__ __align__(16) unsigned char lds[2 * 128 * 128];  // A @0, B @16384
    const int tid = threadIdx.x;
    const int l = tid & 63, wv = tid >> 6, wm = wv >> 1, wn = wv & 1;
    const int bm = blockIdx.y, bn = blockIdx.x;

    // ---- scale (quant_fused finished before this kernel; plain load OK) ----
    const float am = __uint_as_float(*scb);
    const float scl = (fmaxf(am, 1e-12f) / FP8MAX) * wscale[0];

    // ---- staging addresses (global_load_lds, 4 instr each for A and B) ----
    const int srow = l >> 3;                      // 0..7
    const int scol = (16 * (l & 7)) ^ (srow << 4);
    const unsigned char* gA = Aq + (size_t)(bm * 128 + 32 * wv + srow) * 4096 + scol;
    const unsigned char* gB = Bq + (size_t)(bn * 128 + 32 * wv + srow) * 4096 + scol;
    unsigned char* sAw = lds + wv * 4096;         // wave-uniform LDS bases
    unsigned char* sBw = lds + 16384 + wv * 4096;

    // ---- read-side offsets (unchanged, proven) ----
    const int swzR = (l & 7) << 4;
    int aBase[2], bBase[2], rdOff[2][2][2];       // [i][s][half]
    #pragma unroll
    for (int i = 0; i < 2; ++i) {
        aBase[i] = (wm * 64 + i * 32 + (l & 31)) * 128;
        bBase[i] = 16384 + (wn * 64 + i * 32 + (l & 31)) * 128;
        #pragma unroll
        for (int s = 0; s < 2; ++s) {
            int off = s * 64 + (l >> 5) * 32;
            rdOff[i][s][0] = (off) ^ swzR;
            rdOff[i][s][1] = (off + 16) ^ swzR;
        }
    }

    floatx16 acc[2][2];
    #pragma unroll
    for (int i = 0; i < 2; ++i)
        #pragma unroll
        for (int j = 0; j < 2; ++j)
            acc[i][j] = (floatx16)0.f;

    for (int kt = 0; kt < K_DIM / 128; ++kt) {
        __syncthreads();           // all waves done reading previous tile
        #pragma unroll
        for (int i = 0; i < 4; ++i) {
            __builtin_amdgcn_global_load_lds(
                (const __attribute__((address_space(1))) void*)(gA + i * 8 * 4096),
                (__attribute__((address_space(3))) void*)(sAw + i * 1024), 16, 0, 0);
            __builtin_amdgcn_global_load_lds(
                (const __attribute__((address_space(1))) void*)(gB + i * 8 * 4096),
                (__attribute__((address_space(3))) void*)(sBw + i * 1024), 16, 0, 0);
        }
        gA += 128;
        gB += 128;
        __syncthreads();           // vmcnt(0) drain + barrier: tiles visible

        int8v af[2][2], bf[2][2];  // [i|j][s]
        #pragma unroll
        for (int i = 0; i < 2; ++i) {
            #pragma unroll
            for (int s = 0; s < 2; ++s) {
                uint4 u0 = *(const uint4*)(lds + aBase[i] + rdOff[i][s][0]);
                uint4 u1 = *(const uint4*)(lds + aBase[i] + rdOff[i][s][1]);
                af[i][s] = pack8(u0, u1);
                uint4 v0 = *(const uint4*)(lds + bBase[i] + rdOff[i][s][0]);
                uint4 v1 = *(const uint4*)(lds + bBase[i] + rdOff[i][s][1]);
                bf[i][s] = pack8(v0, v1);
            }
        }
        #pragma unroll
        for (int s = 0; s < 2; ++s)
            #pragma unroll
            for (int i = 0; i < 2; ++i)
                #pragma unroll
                for (int j = 0; j < 2; ++j)
                    acc[i][j] = __builtin_amdgcn_mfma_scale_f32_32x32x64_f8f6f4(
                        af[i][s], bf[j][s], acc[i][j],
                        0 /*cbsz: fp8*/, 0 /*blgp: fp8*/,
                        0, 0x7F,   // scale A: E8M0 127 = 1.0
                        0, 0x7F);  // scale B: E8M0 127 = 1.0
    }

    // discriminator. Expected scl ~ 3.1e-6.
    float marker = 0.f;
    if (scl != scl || fabsf(scl) > 1e-1f) marker = 1000.f;
    else if (fabsf(scl) > 1e-4f) marker = 777.f;
    else if (fabsf(scl) < 1e-8f) marker = 333.f;

    float bj[2];
    #pragma unroll
    for (int j = 0; j < 2; ++j)
        bj[j] = bias[bn * 128 + wn * 64 + j * 32 + (l & 31)];

    // C/D map (32x32, shape-determined): col=lane&31, row=(reg&3)+8*(reg>>2)+4*(lane>>5)
    #pragma unroll
    for (int i = 0; i < 2; ++i) {
        #pragma unroll
        for (int rg = 0; rg < 4; ++rg) {
            #pragma unroll
            for (int rr = 0; rr < 4; ++rr) {
                int row = bm * 128 + wm * 64 + i * 32 + rg * 8 + rr + 4 * (l >> 5);
                float* orow = out + (size_t)row * N_DIM;
                #pragma unroll
                for (int j = 0; j < 2; ++j) {
                    int col = bn * 128 + wn * 64 + j * 32 + (l & 31);
                    float v = acc[i][j][rg * 4 + rr] * scl + bj[j];
                    if (marker != 0.f) v = marker;
                    else if (bj[j] != bj[j]) v = 111.f;
                    else if (v != v) v = 555.f;
                    orow[col] = v;
                }
            }
        }
    }
}

// ================= Fallback (in-place spread) path: round-6 verbatim =================

__global__ __launch_bounds__(256) void quant_w_kernel(unsigned char* wbuf) {
    const size_t t = (size_t)blockIdx.x * 256 + threadIdx.x;   // 262144 regions
    uint4* p = (uint4*)(wbuf + t * 256);
    uint4 r[16];
    #pragma unroll
    for (int i = 0; i < 16; ++i) r[i] = p[i];
    const float* f = (const float*)r;
    unsigned int o[32];
    #pragma unroll
    for (int i = 0; i < 16; ++i) {
        unsigned int b0 = f2bfbits(f[4 * i + 0]);
        unsigned int b1 = f2bfbits(f[4 * i + 1]);
        unsigned int b2 = f2bfbits(f[4 * i + 2]);
        unsigned int b3 = f2bfbits(f[4 * i + 3]);
        ((uint2*)o)[i] = make_uint2(b0 | (b1 << 16), b2 | (b3 << 16));
    }
    uint4* q = (uint4*)(wbuf + t * 256);
    #pragma unroll
    for (int i = 0; i < 8; ++i) q[i] = ((uint4*)o)[i];
}

__global__ __launch_bounds__(256) void quant_x_kernel(unsigned char* xbuf, unsigned char* wbuf) {
    const size_t t = (size_t)blockIdx.x * 256 + threadIdx.x;   // 524288 regions
    uint4* p = (uint4*)(xbuf + t * 256);
    uint4 r[16];
    #pragma unroll
    for (int i = 0; i < 16; ++i) r[i] = p[i];
    const float* f = (const float*)r;
    float vmax = 0.f;
    unsigned int o[32];
    #pragma unroll
    for (int i = 0; i < 16; ++i) {
        float a = f[4 * i + 0], b = f[4 * i + 1], c = f[4 * i + 2], d = f[4 * i + 3];
        vmax = fmaxf(vmax, fmaxf(fmaxf(fabsf(a), fabsf(b)), fmaxf(fabsf(c), fabsf(d))));
        ((uint2*)o)[i] = quant4(a, b, c, d);
    }
    uint4* q = (uint4*)(xbuf + t * 256);
    #pragma unroll
    for (int i = 0; i < 8; ++i) q[i] = ((uint4*)o)[i];
    #pragma unroll
    for (int off = 32; off >= 1; off >>= 1)
        vmax = fmaxf(vmax, __shfl_xor(vmax, off, 64));
    __shared__ float smax[4];
    if ((threadIdx.x & 63) == 0) smax[threadIdx.x >> 6] = vmax;
    __syncthreads();
    if (threadIdx.x == 0)
        *(float*)(wbuf + ((size_t)blockIdx.x + 1) * 256 + 128) =
            fmaxf(fmaxf(smax[0], smax[1]), fmaxf(smax[2], smax[3]));
}

__global__ __launch_bounds__(256) void scale_kernel(unsigned char* wbuf, const float* wscale) {
    float vmax = 0.f;
    for (int i = threadIdx.x; i < 2048; i += 256)
        vmax = fmaxf(vmax, *(const float*)(wbuf + ((size_t)i + 1) * 256 + 128));
    #pragma unroll
    for (int off = 32; off >= 1; off >>= 1)
        vmax = fmaxf(vmax, __shfl_xor(vmax, off, 64));
    __shared__ float smax[4];
    if ((threadIdx.x & 63) == 0) smax[threadIdx.x >> 6] = vmax;
    __syncthreads();
    if (threadIdx.x == 0) {
        float m = fmaxf(fmaxf(smax[0], smax[1]), fmaxf(smax[2], smax[3]));
        *(float*)(wbuf + 128) = (fmaxf(m, 1e-12f) / FP8MAX) * wscale[0];
        *(unsigned int*)(wbuf + 132) = CANARY;
    }
}

// ========== Fallback GEMM: round-6 structure, strides parametrized ==========
__global__ __launch_bounds__(256, 2) void gemm_bf16_kernel(
    const unsigned char* __restrict__ Aq,
    const unsigned char* __restrict__ Bq,
    int rs, int ktb,
    const unsigned char* __restrict__ scb,
    const float* __restrict__ bias,
    float* __restrict__ out) {
    __shared__ __align__(16) short lds[2 * 128 * 72];   // A @0, B @9216 (shorts)
    const int tid = threadIdx.x;
    const int l = tid & 63, wv = tid >> 6, wm = wv >> 1, wn = wv & 1;
    const int bm = blockIdx.y, bn = blockIdx.x;
    const int r = tid >> 1, kq = (tid & 1) * 64;

    const float scl = *(const float*)scb;
    const unsigned int canary = *(const unsigned int*)(scb + 4);

    const unsigned char* gA = Aq + (size_t)(bm * 128 + r) * rs + kq;
    const unsigned char* gB = Bq + (size_t)(bn * 128 + r) * rs + kq;
    short* sA = lds + r * 72 + kq / 2;
    short* sB = lds + 9216 + r * 72 + kq / 2;

    int aOff[4][2], bOff[4][2];
    #pragma unroll
    for (int i = 0; i < 4; ++i) {
        #pragma unroll
        for (int s = 0; s < 2; ++s) {
            int rowa = wm * 64 + i * 16 + (l & 15);
            aOff[i][s] = rowa * 72 + s * 32 + (l >> 4) * 8;
            int rowb = wn * 64 + i * 16 + (l & 15);
            bOff[i][s] = 9216 + rowb * 72 + s * 32 + (l >> 4) * 8;
        }
    }

    floatx4 acc[4][4];
    #pragma unroll
    for (int i = 0; i < 4; ++i)
        #pragma unroll
        for (int j = 0; j < 4; ++j)
            acc[i][j] = (floatx4)0.f;

    for (int kt = 0; kt < K_DIM / 64; ++kt) {
        uint4 a0 = *(const uint4*)(gA);
        uint4 a1 = *(const uint4*)(gA + 16);
        uint4 a2 = *(const uint4*)(gA + 32);
        uint4 a3 = *(const uint4*)(gA + 48);
        uint4 b0 = *(const uint4*)(gB);
        uint4 b1 = *(const uint4*)(gB + 16);
        uint4 b2 = *(const uint4*)(gB + 32);
        uint4 b3 = *(const uint4*)(gB + 48);
        gA += ktb;
        gB += ktb;
        __syncthreads();
        *(uint4*)(sA +  0) = a0;  *(uint4*)(sA +  8) = a1;
        *(uint4*)(sA + 16) = a2;  *(uint4*)(sA + 24) = a3;
        *(uint4*)(sB +  0) = b0;  *(uint4*)(sB +  8) = b1;
        *(uint4*)(sB + 16) = b2;  *(uint4*)(sB + 24) = b3;
        __syncthreads();

        short8 af[4][2], bf[4][2];
        #pragma unroll
        for (int i = 0; i < 4; ++i) {
            af[i][0] = *(const short8*)(lds + aOff[i][0]);
            af[i][1] = *(const short8*)(lds + aOff[i][1]);
            bf[i][0] = *(const short8*)(lds + bOff[i][0]);
            bf[i][1] = *(const short8*)(lds + bOff[i][1]);
        }
        #pragma unroll
        for (int s = 0; s < 2; ++s)
            #pragma unroll
            for (int i = 0; i < 4; ++i)
                #pragma unroll
                for (int j = 0; j < 4; ++j)
                    acc[i][j] = __builtin_amdgcn_mfma_f32_16x16x32_bf16(
                        af[i][s], bf[j][s], acc[i][j], 0, 0, 0);
    }

    float marker = 0.f;
    if (canary != CANARY) marker = 222.f;
    else if (scl != scl || fabsf(scl) > 1e-1f) marker = 1000.f;
    else if (fabsf(scl) > 1e-4f) marker = 777.f;
    else if (fabsf(scl) < 1e-8f) marker = 333.f;

    float bj[4];
    #pragma unroll
    for (int j = 0; j < 4; ++j) {
        int col = bn * 128 + wn * 64 + j * 16 + (l & 15);
        bj[j] = bias[col];
    }
    #pragma unroll
    for (int i = 0; i < 4; ++i) {
        #pragma unroll
        for (int rr = 0; rr < 4; ++rr) {
            int row = bm * 128 + wm * 64 + i * 16 + (l >> 4) * 4 + rr;
            float* orow = out + (size_t)row * N_DIM;
            #pragma unroll
            for (int j = 0; j < 4; ++j) {
                int col = bn * 128 + wn * 64 + j * 16 + (l & 15);
                float v = acc[i][j][rr] * scl + bj[j];
                if (marker != 0.f) v = marker;
                else if (bj[j] != bj[j]) v = 111.f;
                else if (v != v) v = 555.f;
                orow[col] = v;
            }
        }
    }
}

extern "C" void kernel_launch(void* const* d_in, const int* in_sizes, int n_in,
                              void* d_out, int out_size, void* d_ws, size_t ws_size,
                              hipStream_t stream) {
    unsigned char* x = (unsigned char*)d_in[0];   // fp32 [8192][4096] (fp16 promoted)
    unsigned char* w = (unsigned char*)d_in[1];   // fp32 exact-fp8 [4096][4096]
    const float* wscale = (const float*)d_in[2];  // fp32 [1]
    const float* bias = (const float*)d_in[3];    // fp32 [4096] (fp16 promoted)
    float* out = (float*)d_out;                   // fp32 [8192][4096]

    const size_t XQ8 = (size_t)M_DIM * K_DIM;     // 32MB fp8 x
    const size_t WQ8 = (size_t)N_DIM * K_DIM;     // 16MB fp8 w
    unsigned char* ws = (unsigned char*)d_ws;

    if (ws_size >= XQ8 + WQ8 + 64) {
        // ---- fp8 compact path: memset(scale) + fused prepass + MX-fp8 GEMM ----
        unsigned char* xq = ws;
        unsigned char* wq = ws + XQ8;
        unsigned int* scb = (unsigned int*)(ws + XQ8 + WQ8);
        hipMemsetAsync(scb, 0, 4, stream);        // seed for atomicMax (graph-safe)
        quant_fused<<<3072, 256, 0, stream>>>((const uint4*)x, (const uint4*)w,
                                              (uint4*)xq, (uint4*)wq, scb);
        gemm_fp8_kernel<<<dim3(N_DIM / 128, M_DIM / 128), 256, 0, stream>>>(
            xq, wq, scb, wscale, bias, out);
    } else {
        // ---- fallback: round-6 in-place spread path (proven) ----
        quant_w_kernel<<<1024, 256, 0, stream>>>(w);
        quant_x_kernel<<<2048, 256, 0, stream>>>(x, w);
        scale_kernel<<<1, 256, 0, stream>>>(w, wscale);
        gemm_bf16_kernel<<<dim3(N_DIM / 128, M_DIM / 128), 256, 0, stream>>>(
            x, w, 16384, 256, w + 128, bias, out);
    }
}